// Round 4
// baseline (71464.746 us; speedup 1.0000x reference)
//
#include <hip/hip_runtime.h>
#include <hip/hip_fp16.h>
#include <stdint.h>

#define B_  32
#define T_  2000
#define H_  512
#define NH_ 100
#define NM_ 65

typedef _Float16 f16x8 __attribute__((ext_vector_type(8)));
typedef _Float16 f16x2 __attribute__((ext_vector_type(2)));
typedef float    f32x4 __attribute__((ext_vector_type(4)));

typedef __attribute__((address_space(3))) void lds_void_t;
typedef __attribute__((address_space(1))) void glb_void_t;

__device__ __forceinline__ void gload_lds16(const void* g, void* l) {
  __builtin_amdgcn_global_load_lds((const glb_void_t*)g, (lds_void_t*)l, 16, 0, 0);
}

__device__ __forceinline__ float sigmoidf_(float x) {
  float e = __builtin_amdgcn_exp2f(-x * 1.44269504f);
  return __builtin_amdgcn_rcpf(1.0f + e);
}
__device__ __forceinline__ float tanhf_(float x) {
  float e = __builtin_amdgcn_exp2f(x * 2.88539008f);
  return 1.0f - 2.0f * __builtin_amdgcn_rcpf(e + 1.0f);
}
__device__ __forceinline__ float dot2(unsigned w, unsigned h, float acc) {
  return __builtin_amdgcn_fdot2(__builtin_bit_cast(f16x2, w),
                                __builtin_bit_cast(f16x2, h), acc, false);
}
__device__ __forceinline__ unsigned pack2(float a, float b) {
  __half2 h = __floats2half2_rn(a, b);
  return __builtin_bit_cast(unsigned, h);
}

// ---------------- hypernetwork ----------------
__global__ void hyper1(const float* __restrict__ es, const float* __restrict__ W1,
                       const float* __restrict__ b1, float* __restrict__ hE) {
  int b = blockIdx.x, o = threadIdx.x;   // 32 x 256
  float a = b1[o];
  #pragma unroll
  for (int c = 0; c < 16; ++c) a += es[b*16 + c] * W1[o*16 + c];
  hE[b*256 + o] = fmaxf(a, 0.f);
}

__global__ void hyper2(const float* __restrict__ hE,
                       const float* __restrict__ Wbh, const float* __restrict__ bbh,
                       const float* __restrict__ harmb,
                       const float* __restrict__ Wbn, const float* __restrict__ bbn,
                       const float* __restrict__ noiseb, float* __restrict__ effb) {
  int b = blockIdx.x, o = threadIdx.x;
  if (o < NH_) {
    float a = bbh[o] + harmb[o];
    for (int c = 0; c < 256; ++c) a += hE[b*256 + c] * Wbh[o*256 + c];
    effb[b*256 + o] = a;
  } else if (o < NH_ + NM_) {
    int q = o - NH_;
    float a = bbn[q] + noiseb[q];
    for (int c = 0; c < 256; ++c) a += hE[b*256 + c] * Wbn[q*256 + c];
    effb[b*256 + o] = a;
  }
}

// effW[b][o_base+o][h] = baseW[o*512+h] + bd[row] + sum_c Wd[row][c]*hE[b][c]
__global__ __launch_bounds__(256) void hyper3(
    const float* __restrict__ hE, const float* __restrict__ Wd,
    const float* __restrict__ bd, const float* __restrict__ baseW,
    __half* __restrict__ effW, int o_base) {
  __shared__ float wl[256*33];
  __shared__ float hEl[32*256];
  int tid = threadIdx.x;
  int row0 = blockIdx.x * 256;
  #pragma unroll
  for (int i = 0; i < 32; ++i) hEl[i*256 + tid] = hE[i*256 + tid];
  float acc[32];
  #pragma unroll
  for (int b = 0; b < 32; ++b) acc[b] = 0.f;
  for (int cc = 0; cc < 256; cc += 32) {
    __syncthreads();
    #pragma unroll
    for (int i = 0; i < 32; ++i) {
      int idx = i*256 + tid;
      int r = idx >> 5, c = idx & 31;
      wl[r*33 + c] = Wd[(size_t)(row0 + r)*256 + cc + c];
    }
    __syncthreads();
    #pragma unroll
    for (int c = 0; c < 32; ++c) {
      float w = wl[tid*33 + c];
      #pragma unroll
      for (int b = 0; b < 32; ++b) acc[b] += w * hEl[b*256 + cc + c];
    }
  }
  int row = row0 + tid;
  int o = row >> 9, h = row & 511;
  float base = baseW[row] + bd[row];
  #pragma unroll
  for (int b = 0; b < 32; ++b) {
    effW[((size_t)b*256 + o_base + o)*512 + h] = (__half)(acc[b] + base);
  }
}

// ---------------- converts ----------------
__global__ void cvt_f16(const float* __restrict__ in, __half* __restrict__ out, int n) {
  int i = blockIdx.x*256 + threadIdx.x;
  if (i < n) out[i] = (__half)in[i];
}

// Wp4[q][t], q = r*32+jj (r=gate-row block, jj=k-quad), t = hf*512+u
__global__ void pack_whh(const float* __restrict__ Whh, uint4* __restrict__ Wp4) {
  int idx = blockIdx.x*256 + threadIdx.x;    // 96*1024
  int q = idx >> 10, t = idx & 1023;
  int r = q >> 5, jj = q & 31;
  int u = t & 511, hf = t >> 9;
  int row = u + r*512;
  int k0 = hf*256 + jj*8;
  const float* src = Whh + (size_t)row*512 + k0;
  uint4 out;
  out.x = pack2(src[0], src[1]);
  out.y = pack2(src[2], src[3]);
  out.z = pack2(src[4], src[5]);
  out.w = pack2(src[6], src[7]);
  Wp4[idx] = out;
}

// ---------------- pre layer (per chunk) ----------------
__global__ void pre_kernel(const float* __restrict__ f0, const float* __restrict__ loud,
                           const float* __restrict__ preW, const float* __restrict__ preb,
                           __half* __restrict__ xpre, int CH, int c0) {
  int b = blockIdx.y;
  int idx = blockIdx.x*256 + threadIdx.x;    // CH*512
  int t = idx >> 9, h = idx & 511;
  int mg = b*T_ + c0 + t;
  float v = f0[mg]*preW[h*2+0] + loud[mg]*preW[h*2+1] + preb[h];
  v = v >= 0.f ? v : 0.01f*v;
  xpre[((size_t)b*CH + t)*512 + h] = (__half)v;
}

// ---------------- trunk GEMM (NT, K=512, 128x128 tile, f16 MFMA) ----------------
// A [M][512], B [N][512], C [M][N] f16 (+bias, ACT: 0 none, 1 leaky)
template<int ACT>
__global__ __launch_bounds__(256) void gemm_nt(
    const __half* __restrict__ A, const __half* __restrict__ B,
    __half* __restrict__ C, const float* __restrict__ bias, int N) {
  constexpr int K = 512;
  __shared__ __align__(16) __half As[128*64];
  __shared__ __align__(16) __half Bs[128*64];
  int tid = threadIdx.x;
  int bx = blockIdx.x, by = blockIdx.y;
  const __half* Ab = A + (size_t)bx*128*K;
  const __half* Bb = B + (size_t)by*128*K;
  f32x4 acc[4][4] = {};
  int lane = tid & 63;
  int wv = tid >> 6, wr = wv >> 1, wc = wv & 1;
  int lr = lane & 15, lk = lane >> 4;

  for (int kt = 0; kt < K/64; ++kt) {
    #pragma unroll
    for (int j = 0; j < 4; ++j) {
      int idx = j*256 + tid;
      int row = idx >> 3, seg = idx & 7;
      const __half* gpA = Ab + (size_t)row*K + kt*64 + seg*8;
      const __half* gpB = Bb + (size_t)row*K + kt*64 + seg*8;
      __half* lpA = As + (size_t)(j*256 + (tid & ~63))*8;
      __half* lpB = Bs + (size_t)(j*256 + (tid & ~63))*8;
      gload_lds16(gpA, lpA);
      gload_lds16(gpB, lpB);
    }
    __syncthreads();
    #pragma unroll
    for (int ks = 0; ks < 2; ++ks) {
      f16x8 af[4], bf[4];
      #pragma unroll
      for (int i = 0; i < 4; ++i)
        af[i] = *(const f16x8*)(As + (wr*64 + i*16 + lr)*64 + ks*32 + lk*8);
      #pragma unroll
      for (int j2 = 0; j2 < 4; ++j2)
        bf[j2] = *(const f16x8*)(Bs + (wc*64 + j2*16 + lr)*64 + ks*32 + lk*8);
      #pragma unroll
      for (int i = 0; i < 4; ++i)
        #pragma unroll
        for (int j2 = 0; j2 < 4; ++j2)
          acc[i][j2] = __builtin_amdgcn_mfma_f32_16x16x32_f16(af[i], bf[j2], acc[i][j2], 0, 0, 0);
    }
    __syncthreads();
  }

  #pragma unroll
  for (int j2 = 0; j2 < 4; ++j2) {
    int col = by*128 + wc*64 + j2*16 + lr;
    float bv = bias[col];
    #pragma unroll
    for (int i = 0; i < 4; ++i) {
      int row0 = bx*128 + wr*64 + i*16 + lk*4;
      #pragma unroll
      for (int r = 0; r < 4; ++r) {
        float v = acc[i][j2][r] + bv;
        if (ACT == 1) v = v >= 0.f ? v : 0.01f*v;
        C[(size_t)(row0 + r)*N + col] = (__half)v;
      }
    }
  }
}

// ---------------- heads GEMM: per-batch modulated weights, sigmoid, fp32 out ----------------
__global__ __launch_bounds__(256) void heads_gemm(
    const __half* __restrict__ Apc, const __half* __restrict__ effW,
    const float* __restrict__ effb, float* __restrict__ out, int CH, int c0) {
  constexpr int K = 512;
  __shared__ __align__(16) __half As[128*64];
  __shared__ __align__(16) __half Bs[128*64];
  int tid = threadIdx.x;
  int bx = blockIdx.x, by = blockIdx.y, b = blockIdx.z;
  const __half* Ab = Apc + (size_t)b*CH*K;
  const __half* Bb = effW + ((size_t)b*256 + (size_t)by*128)*K;
  f32x4 acc[4][4] = {};
  int lane = tid & 63;
  int wv = tid >> 6, wr = wv >> 1, wc = wv & 1;
  int lr = lane & 15, lk = lane >> 4;

  for (int kt = 0; kt < K/64; ++kt) {
    #pragma unroll
    for (int j = 0; j < 4; ++j) {
      int idx = j*256 + tid;
      int row = idx >> 3, seg = idx & 7;
      int ar = bx*128 + row; if (ar > CH-1) ar = CH-1;   // clamp (dup reads, masked stores)
      const __half* gpA = Ab + (size_t)ar*K + kt*64 + seg*8;
      const __half* gpB = Bb + (size_t)row*K + kt*64 + seg*8;
      __half* lpA = As + (size_t)(j*256 + (tid & ~63))*8;
      __half* lpB = Bs + (size_t)(j*256 + (tid & ~63))*8;
      gload_lds16(gpA, lpA);
      gload_lds16(gpB, lpB);
    }
    __syncthreads();
    #pragma unroll
    for (int ks = 0; ks < 2; ++ks) {
      f16x8 af[4], bf[4];
      #pragma unroll
      for (int i = 0; i < 4; ++i)
        af[i] = *(const f16x8*)(As + (wr*64 + i*16 + lr)*64 + ks*32 + lk*8);
      #pragma unroll
      for (int j2 = 0; j2 < 4; ++j2)
        bf[j2] = *(const f16x8*)(Bs + (wc*64 + j2*16 + lr)*64 + ks*32 + lk*8);
      #pragma unroll
      for (int i = 0; i < 4; ++i)
        #pragma unroll
        for (int j2 = 0; j2 < 4; ++j2)
          acc[i][j2] = __builtin_amdgcn_mfma_f32_16x16x32_f16(af[i], bf[j2], acc[i][j2], 0, 0, 0);
    }
    __syncthreads();
  }

  #pragma unroll
  for (int j2 = 0; j2 < 4; ++j2) {
    int o = by*128 + wc*64 + j2*16 + lr;
    if (o < NH_ + NM_) {
      float bv = effb[b*256 + o];
      #pragma unroll
      for (int i = 0; i < 4; ++i) {
        #pragma unroll
        for (int r = 0; r < 4; ++r) {
          int trow = bx*128 + wr*64 + i*16 + lk*4 + r;
          if (trow < CH) {
            int tg = c0 + trow;
            float v = sigmoidf_(acc[i][j2][r] + bv);
            if (o < NH_)
              out[((size_t)b*T_ + tg)*NH_ + o] = v;
            else
              out[(size_t)B_*T_*NH_ + ((size_t)b*T_ + tg)*NM_ + (o - NH_)] = v;
          }
        }
      }
    }
  }
}

// ---------------- GRU scan (chunked): 32 WGs x 1024 threads, W_hh in VGPRs ----------------
// Weights as 96 NAMED uint4 locals (X-macros): SSA values, never touch SROA/alloca
// (rounds 2-3 showed arrays land in scratch: VGPR_Count=64, per-step scratch re-read).
// waves_per_eu(4,4): 4 waves/SIMD -> 512-VGPR budget; demand ~430.
#define DECL_J(j) \
  uint4 w0_##j = Wp4[(size_t)(j)*1024 + t]; \
  uint4 w1_##j = Wp4[(size_t)(32 + (j))*1024 + t]; \
  uint4 w2_##j = Wp4[(size_t)(64 + (j))*1024 + t];

#define DOT_J(j) { uint4 hv = hp4[hbase + (j)]; \
  a0 = dot2(w0_##j.x, hv.x, a0); a0 = dot2(w0_##j.y, hv.y, a0); \
  a0 = dot2(w0_##j.z, hv.z, a0); a0 = dot2(w0_##j.w, hv.w, a0); \
  a1 = dot2(w1_##j.x, hv.x, a1); a1 = dot2(w1_##j.y, hv.y, a1); \
  a1 = dot2(w1_##j.z, hv.z, a1); a1 = dot2(w1_##j.w, hv.w, a1); \
  a2 = dot2(w2_##j.x, hv.x, a2); a2 = dot2(w2_##j.y, hv.y, a2); \
  a2 = dot2(w2_##j.z, hv.z, a2); a2 = dot2(w2_##j.w, hv.w, a2); }

__global__ __launch_bounds__(1024) __attribute__((amdgpu_waves_per_eu(4, 4)))
void gru_scan(
    const uint4* __restrict__ Wp4, const __half* __restrict__ gi_c,
    const float* __restrict__ bhh, __half* __restrict__ ys_c,
    float* __restrict__ hstate, int CH, int first) {
  int b = blockIdx.x;
  int t = threadIdx.x;
  int u = t & 511;
  int hf = t >> 9;
  int hbase = hf << 5;

  __shared__ __align__(16) unsigned hp[256];   // packed f16x2 hidden state (512 halfs)
  __shared__ float part[512*3];

  DECL_J(0)  DECL_J(1)  DECL_J(2)  DECL_J(3)  DECL_J(4)  DECL_J(5)  DECL_J(6)  DECL_J(7)
  DECL_J(8)  DECL_J(9)  DECL_J(10) DECL_J(11) DECL_J(12) DECL_J(13) DECL_J(14) DECL_J(15)
  DECL_J(16) DECL_J(17) DECL_J(18) DECL_J(19) DECL_J(20) DECL_J(21) DECL_J(22) DECL_J(23)
  DECL_J(24) DECL_J(25) DECL_J(26) DECL_J(27) DECL_J(28) DECL_J(29) DECL_J(30) DECL_J(31)

  float bh0 = bhh[u], bh1 = bhh[u + 512], bh2 = bhh[u + 1024];
  float hreg = 0.f;
  if (!hf) {
    hreg = first ? 0.f : hstate[b*512 + u];
    ((__half*)hp)[u] = (__half)hreg;
  }
  __syncthreads();

  const __half* gib = gi_c + (size_t)b*CH*1536;
  __half* ysb = ys_c + (size_t)b*CH*512;
  const uint4* hp4 = (const uint4*)hp;

  for (int s = 0; s < CH; ++s) {
    // gi loads issue here; consumed after the dot chain -> HBM latency hidden
    float gir = 0.f, giz = 0.f, gin = 0.f;
    if (hf == 0) {
      const __half* g = gib + (size_t)s*1536 + u;
      gir = (float)g[0]; giz = (float)g[512]; gin = (float)g[1024];
    }
    float a0 = 0.f, a1 = 0.f, a2 = 0.f;
    DOT_J(0)  DOT_J(1)  DOT_J(2)  DOT_J(3)  DOT_J(4)  DOT_J(5)  DOT_J(6)  DOT_J(7)
    DOT_J(8)  DOT_J(9)  DOT_J(10) DOT_J(11) DOT_J(12) DOT_J(13) DOT_J(14) DOT_J(15)
    DOT_J(16) DOT_J(17) DOT_J(18) DOT_J(19) DOT_J(20) DOT_J(21) DOT_J(22) DOT_J(23)
    DOT_J(24) DOT_J(25) DOT_J(26) DOT_J(27) DOT_J(28) DOT_J(29) DOT_J(30) DOT_J(31)
    if (hf) { part[u*3+0] = a0; part[u*3+1] = a1; part[u*3+2] = a2; }
    __syncthreads();
    if (!hf) {
      float ghr = a0 + part[u*3+0] + bh0;
      float ghz = a1 + part[u*3+1] + bh1;
      float ghn = a2 + part[u*3+2] + bh2;
      float r = sigmoidf_(gir + ghr);
      float z = sigmoidf_(giz + ghz);
      float n = tanhf_(gin + r*ghn);
      hreg = (1.f - z)*n + z*hreg;
      ysb[(size_t)s*512 + u] = (__half)hreg;
      ((__half*)hp)[u] = (__half)hreg;
    }
    __syncthreads();
  }
  if (!hf) hstate[b*512 + u] = hreg;
}

// ---------------- launch ----------------
extern "C" void kernel_launch(void* const* d_in, const int* in_sizes, int n_in,
                              void* d_out, int out_size, void* d_ws, size_t ws_size,
                              hipStream_t stream) {
  const float* f0     = (const float*)d_in[0];
  const float* loud   = (const float*)d_in[1];
  const float* es     = (const float*)d_in[2];
  const float* preW   = (const float*)d_in[3];
  const float* preb   = (const float*)d_in[4];
  const float* Wih    = (const float*)d_in[5];
  const float* Whh    = (const float*)d_in[6];
  const float* b_ih   = (const float*)d_in[7];
  const float* b_hh   = (const float*)d_in[8];
  const float* postW  = (const float*)d_in[9];
  const float* postb  = (const float*)d_in[10];
  const float* harmW  = (const float*)d_in[11];
  const float* harmb  = (const float*)d_in[12];
  const float* noiseW = (const float*)d_in[13];
  const float* noiseb = (const float*)d_in[14];
  const float* hypW1  = (const float*)d_in[15];
  const float* hypb1  = (const float*)d_in[16];
  const float* Wdh    = (const float*)d_in[17];
  const float* bdh    = (const float*)d_in[18];
  const float* Wbh    = (const float*)d_in[19];
  const float* bbh    = (const float*)d_in[20];
  const float* Wdn    = (const float*)d_in[21];
  const float* bdn    = (const float*)d_in[22];
  const float* Wbn    = (const float*)d_in[23];
  const float* bbn    = (const float*)d_in[24];
  (void)in_sizes; (void)n_in; (void)out_size;

  // ---- workspace layout (chunked; CH picked to fit ws_size) ----
  const size_t FIXED = 12288ull*1024ull;   // ~12 MB fixed region
  int CH = 20;
  {
    const int opts[8] = {2000, 1000, 500, 400, 200, 100, 40, 20};
    for (int i = 0; i < 8; ++i) {
      size_t need = FIXED + (size_t)opts[i] * 163840ull + 65536ull;
      if (need <= ws_size) { CH = opts[i]; break; }
    }
  }
  const int NC = T_ / CH;
  const int Mc = B_ * CH;

  char* w = (char*)d_ws;
  size_t off = 0;
  auto alloc = [&](size_t bytes) -> void* {
    void* p = (void*)(w + off);
    off += (bytes + 255) & ~(size_t)255;
    return p;
  };
  float*  hE      = (float*)alloc((size_t)32*256*4);
  float*  effb    = (float*)alloc((size_t)32*256*4);
  float*  hstate  = (float*)alloc((size_t)32*512*4);
  __half* effW    = (__half*)alloc((size_t)32*256*512*2);
  __half* Wih16   = (__half*)alloc((size_t)1536*512*2);
  __half* postW16 = (__half*)alloc((size_t)512*512*2);
  uint4*  Wp4     = (uint4*)alloc((size_t)96*1024*16);
  __half* xpre    = (__half*)alloc((size_t)Mc*512*2);   // aliased: post GEMM output
  __half* gibuf   = (__half*)alloc((size_t)Mc*1536*2);
  __half* ysbuf   = (__half*)alloc((size_t)Mc*512*2);
  __half* postc   = xpre;   // xpre dead after gi GEMM

  // ---- prologue (weights, hypernet) ----
  hyper1<<<32, 256, 0, stream>>>(es, hypW1, hypb1, hE);
  hyper2<<<32, 256, 0, stream>>>(hE, Wbh, bbh, harmb, Wbn, bbn, noiseb, effb);
  hyper3<<<200, 256, 0, stream>>>(hE, Wdh, bdh, harmW, effW, 0);
  hyper3<<<130, 256, 0, stream>>>(hE, Wdn, bdn, noiseW, effW, NH_);
  cvt_f16<<<(1536*512)/256, 256, 0, stream>>>(Wih, Wih16, 1536*512);
  cvt_f16<<<(512*512)/256, 256, 0, stream>>>(postW, postW16, 512*512);
  pack_whh<<<384, 256, 0, stream>>>(Whh, Wp4);

  // ---- chunked trunk ----
  for (int c = 0; c < NC; ++c) {
    int c0 = c * CH;
    pre_kernel<<<dim3(CH*2, 32), 256, 0, stream>>>(f0, loud, preW, preb, xpre, CH, c0);
    gemm_nt<0><<<dim3(Mc/128, 12), 256, 0, stream>>>(xpre, Wih16, gibuf, b_ih, 1536);
    gru_scan<<<32, 1024, 0, stream>>>(Wp4, gibuf, b_hh, ysbuf, hstate, CH, c == 0 ? 1 : 0);
    gemm_nt<1><<<dim3(Mc/128, 4), 256, 0, stream>>>(ysbuf, postW16, postc, postb, 512);
    heads_gemm<<<dim3((CH+127)/128, 2, 32), 256, 0, stream>>>(postc, effW, effb,
                                                              (float*)d_out, CH, c0);
  }
}

// Round 5
// 25079.099 us; speedup vs baseline: 2.8496x; 2.8496x over previous
//
#include <hip/hip_runtime.h>
#include <hip/hip_fp16.h>
#include <stdint.h>

#define B_  32
#define T_  2000
#define H_  512
#define NH_ 100
#define NM_ 65

typedef _Float16 f16x8 __attribute__((ext_vector_type(8)));
typedef _Float16 f16x2 __attribute__((ext_vector_type(2)));
typedef float    f32x4 __attribute__((ext_vector_type(4)));

typedef __attribute__((address_space(3))) void lds_void_t;
typedef __attribute__((address_space(1))) void glb_void_t;

__device__ __forceinline__ void gload_lds16(const void* g, void* l) {
  __builtin_amdgcn_global_load_lds((const glb_void_t*)g, (lds_void_t*)l, 16, 0, 0);
}

__device__ __forceinline__ float sigmoidf_(float x) {
  float e = __builtin_amdgcn_exp2f(-x * 1.44269504f);
  return __builtin_amdgcn_rcpf(1.0f + e);
}
__device__ __forceinline__ float tanhf_(float x) {
  float e = __builtin_amdgcn_exp2f(x * 2.88539008f);
  return 1.0f - 2.0f * __builtin_amdgcn_rcpf(e + 1.0f);
}
__device__ __forceinline__ float dot2(unsigned w, unsigned h, float acc) {
  return __builtin_amdgcn_fdot2(__builtin_bit_cast(f16x2, w),
                                __builtin_bit_cast(f16x2, h), acc, false);
}
__device__ __forceinline__ unsigned pack2(float a, float b) {
  __half2 h = __floats2half2_rn(a, b);
  return __builtin_bit_cast(unsigned, h);
}
__device__ __forceinline__ unsigned pack2h(__half a, __half b) {
  __half2 h2; h2.x = a; h2.y = b;
  return __builtin_bit_cast(unsigned, h2);
}
__device__ __forceinline__ float hsel(unsigned w, int hi) {
  __half2 h2 = __builtin_bit_cast(__half2, w);
  return hi ? __high2float(h2) : __low2float(h2);
}

// ---------------- hypernetwork ----------------
__global__ void hyper1(const float* __restrict__ es, const float* __restrict__ W1,
                       const float* __restrict__ b1, float* __restrict__ hE) {
  int b = blockIdx.x, o = threadIdx.x;   // 32 x 256
  float a = b1[o];
  #pragma unroll
  for (int c = 0; c < 16; ++c) a += es[b*16 + c] * W1[o*16 + c];
  hE[b*256 + o] = fmaxf(a, 0.f);
}

__global__ void hyper2(const float* __restrict__ hE,
                       const float* __restrict__ Wbh, const float* __restrict__ bbh,
                       const float* __restrict__ harmb,
                       const float* __restrict__ Wbn, const float* __restrict__ bbn,
                       const float* __restrict__ noiseb, float* __restrict__ effb) {
  int b = blockIdx.x, o = threadIdx.x;
  if (o < NH_) {
    float a = bbh[o] + harmb[o];
    for (int c = 0; c < 256; ++c) a += hE[b*256 + c] * Wbh[o*256 + c];
    effb[b*256 + o] = a;
  } else if (o < NH_ + NM_) {
    int q = o - NH_;
    float a = bbn[q] + noiseb[q];
    for (int c = 0; c < 256; ++c) a += hE[b*256 + c] * Wbn[q*256 + c];
    effb[b*256 + o] = a;
  }
}

// effW[b][o_base+o][h] = baseW[o*512+h] + bd[row] + sum_c Wd[row][c]*hE[b][c]
__global__ __launch_bounds__(256) void hyper3(
    const float* __restrict__ hE, const float* __restrict__ Wd,
    const float* __restrict__ bd, const float* __restrict__ baseW,
    __half* __restrict__ effW, int o_base) {
  __shared__ float wl[256*33];
  __shared__ float hEl[32*256];
  int tid = threadIdx.x;
  int row0 = blockIdx.x * 256;
  #pragma unroll
  for (int i = 0; i < 32; ++i) hEl[i*256 + tid] = hE[i*256 + tid];
  float acc[32];
  #pragma unroll
  for (int b = 0; b < 32; ++b) acc[b] = 0.f;
  for (int cc = 0; cc < 256; cc += 32) {
    __syncthreads();
    #pragma unroll
    for (int i = 0; i < 32; ++i) {
      int idx = i*256 + tid;
      int r = idx >> 5, c = idx & 31;
      wl[r*33 + c] = Wd[(size_t)(row0 + r)*256 + cc + c];
    }
    __syncthreads();
    #pragma unroll
    for (int c = 0; c < 32; ++c) {
      float w = wl[tid*33 + c];
      #pragma unroll
      for (int b = 0; b < 32; ++b) acc[b] += w * hEl[b*256 + cc + c];
    }
  }
  int row = row0 + tid;
  int o = row >> 9, h = row & 511;
  float base = baseW[row] + bd[row];
  #pragma unroll
  for (int b = 0; b < 32; ++b) {
    effW[((size_t)b*256 + o_base + o)*512 + h] = (__half)(acc[b] + base);
  }
}

// ---------------- converts ----------------
__global__ void cvt_f16(const float* __restrict__ in, __half* __restrict__ out, int n) {
  int i = blockIdx.x*256 + threadIdx.x;
  if (i < n) out[i] = (__half)in[i];
}

// Wp2[((g*2+hh)*32 + j)*512 + i]: thread i of role (g,hh) gets col-quad j.
// i = ch*256 + u; row = g*512 + hh*256 + u; cols = ch*256 + j*8 .. +8
__global__ void pack_whh2(const float* __restrict__ Whh, uint4* __restrict__ Wp2) {
  int idx = blockIdx.x*256 + threadIdx.x;    // 3*2*32*512 = 98304
  int i  = idx & 511;
  int j  = (idx >> 9) & 31;
  int hh = (idx >> 14) & 1;
  int g  = idx >> 15;
  int u = i & 255, ch = i >> 8;
  int row = g*512 + hh*256 + u;
  int col0 = ch*256 + j*8;
  const float* src = Whh + (size_t)row*512 + col0;
  uint4 o;
  o.x = pack2(src[0], src[1]);
  o.y = pack2(src[2], src[3]);
  o.z = pack2(src[4], src[5]);
  o.w = pack2(src[6], src[7]);
  Wp2[idx] = o;
}

// ---------------- pre layer (per chunk) ----------------
__global__ void pre_kernel(const float* __restrict__ f0, const float* __restrict__ loud,
                           const float* __restrict__ preW, const float* __restrict__ preb,
                           __half* __restrict__ xpre, int CH, int c0) {
  int b = blockIdx.y;
  int idx = blockIdx.x*256 + threadIdx.x;    // CH*512
  int t = idx >> 9, h = idx & 511;
  int mg = b*T_ + c0 + t;
  float v = f0[mg]*preW[h*2+0] + loud[mg]*preW[h*2+1] + preb[h];
  v = v >= 0.f ? v : 0.01f*v;
  xpre[((size_t)b*CH + t)*512 + h] = (__half)v;
}

// ---------------- trunk GEMM (NT, K=512, 128x128 tile, f16 MFMA) ----------------
template<int ACT>
__global__ __launch_bounds__(256) void gemm_nt(
    const __half* __restrict__ A, const __half* __restrict__ B,
    __half* __restrict__ C, const float* __restrict__ bias, int N) {
  constexpr int K = 512;
  __shared__ __align__(16) __half As[128*64];
  __shared__ __align__(16) __half Bs[128*64];
  int tid = threadIdx.x;
  int bx = blockIdx.x, by = blockIdx.y;
  const __half* Ab = A + (size_t)bx*128*K;
  const __half* Bb = B + (size_t)by*128*K;
  f32x4 acc[4][4] = {};
  int lane = tid & 63;
  int wv = tid >> 6, wr = wv >> 1, wc = wv & 1;
  int lr = lane & 15, lk = lane >> 4;

  for (int kt = 0; kt < K/64; ++kt) {
    #pragma unroll
    for (int j = 0; j < 4; ++j) {
      int idx = j*256 + tid;
      int row = idx >> 3, seg = idx & 7;
      const __half* gpA = Ab + (size_t)row*K + kt*64 + seg*8;
      const __half* gpB = Bb + (size_t)row*K + kt*64 + seg*8;
      __half* lpA = As + (size_t)(j*256 + (tid & ~63))*8;
      __half* lpB = Bs + (size_t)(j*256 + (tid & ~63))*8;
      gload_lds16(gpA, lpA);
      gload_lds16(gpB, lpB);
    }
    __syncthreads();
    #pragma unroll
    for (int ks = 0; ks < 2; ++ks) {
      f16x8 af[4], bf[4];
      #pragma unroll
      for (int i = 0; i < 4; ++i)
        af[i] = *(const f16x8*)(As + (wr*64 + i*16 + lr)*64 + ks*32 + lk*8);
      #pragma unroll
      for (int j2 = 0; j2 < 4; ++j2)
        bf[j2] = *(const f16x8*)(Bs + (wc*64 + j2*16 + lr)*64 + ks*32 + lk*8);
      #pragma unroll
      for (int i = 0; i < 4; ++i)
        #pragma unroll
        for (int j2 = 0; j2 < 4; ++j2)
          acc[i][j2] = __builtin_amdgcn_mfma_f32_16x16x32_f16(af[i], bf[j2], acc[i][j2], 0, 0, 0);
    }
    __syncthreads();
  }

  #pragma unroll
  for (int j2 = 0; j2 < 4; ++j2) {
    int col = by*128 + wc*64 + j2*16 + lr;
    float bv = bias[col];
    #pragma unroll
    for (int i = 0; i < 4; ++i) {
      int row0 = bx*128 + wr*64 + i*16 + lk*4;
      #pragma unroll
      for (int r = 0; r < 4; ++r) {
        float v = acc[i][j2][r] + bv;
        if (ACT == 1) v = v >= 0.f ? v : 0.01f*v;
        C[(size_t)(row0 + r)*N + col] = (__half)v;
      }
    }
  }
}

// ---------------- heads GEMM: per-batch modulated weights, sigmoid, fp32 out ----------------
__global__ __launch_bounds__(256) void heads_gemm(
    const __half* __restrict__ Apc, const __half* __restrict__ effW,
    const float* __restrict__ effb, float* __restrict__ out, int CH, int c0) {
  constexpr int K = 512;
  __shared__ __align__(16) __half As[128*64];
  __shared__ __align__(16) __half Bs[128*64];
  int tid = threadIdx.x;
  int bx = blockIdx.x, by = blockIdx.y, b = blockIdx.z;
  const __half* Ab = Apc + (size_t)b*CH*K;
  const __half* Bb = effW + ((size_t)b*256 + (size_t)by*128)*K;
  f32x4 acc[4][4] = {};
  int lane = tid & 63;
  int wv = tid >> 6, wr = wv >> 1, wc = wv & 1;
  int lr = lane & 15, lk = lane >> 4;

  for (int kt = 0; kt < K/64; ++kt) {
    #pragma unroll
    for (int j = 0; j < 4; ++j) {
      int idx = j*256 + tid;
      int row = idx >> 3, seg = idx & 7;
      int ar = bx*128 + row; if (ar > CH-1) ar = CH-1;
      const __half* gpA = Ab + (size_t)ar*K + kt*64 + seg*8;
      const __half* gpB = Bb + (size_t)row*K + kt*64 + seg*8;
      __half* lpA = As + (size_t)(j*256 + (tid & ~63))*8;
      __half* lpB = Bs + (size_t)(j*256 + (tid & ~63))*8;
      gload_lds16(gpA, lpA);
      gload_lds16(gpB, lpB);
    }
    __syncthreads();
    #pragma unroll
    for (int ks = 0; ks < 2; ++ks) {
      f16x8 af[4], bf[4];
      #pragma unroll
      for (int i = 0; i < 4; ++i)
        af[i] = *(const f16x8*)(As + (wr*64 + i*16 + lr)*64 + ks*32 + lk*8);
      #pragma unroll
      for (int j2 = 0; j2 < 4; ++j2)
        bf[j2] = *(const f16x8*)(Bs + (wc*64 + j2*16 + lr)*64 + ks*32 + lk*8);
      #pragma unroll
      for (int i = 0; i < 4; ++i)
        #pragma unroll
        for (int j2 = 0; j2 < 4; ++j2)
          acc[i][j2] = __builtin_amdgcn_mfma_f32_16x16x32_f16(af[i], bf[j2], acc[i][j2], 0, 0, 0);
    }
    __syncthreads();
  }

  #pragma unroll
  for (int j2 = 0; j2 < 4; ++j2) {
    int o = by*128 + wc*64 + j2*16 + lr;
    if (o < NH_ + NM_) {
      float bv = effb[b*256 + o];
      #pragma unroll
      for (int i = 0; i < 4; ++i) {
        #pragma unroll
        for (int r = 0; r < 4; ++r) {
          int trow = bx*128 + wr*64 + i*16 + lk*4 + r;
          if (trow < CH) {
            int tg = c0 + trow;
            float v = sigmoidf_(acc[i][j2][r] + bv);
            if (o < NH_)
              out[((size_t)b*T_ + tg)*NH_ + o] = v;
            else
              out[(size_t)B_*T_*NH_ + ((size_t)b*T_ + tg)*NM_ + (o - NH_)] = v;
          }
        }
      }
    }
  }
}

// ---------------- GRU scan: 6 WGs per batch (gate x half), spin-synced ----------------
// Per-CU register file is 512 KB -> full W_hh (1.57 MB f16) can NEVER be CU-resident
// (root cause of rounds 2-4: forced spill, 33 us/step HBM-bound). Split: WG = one
// gate (r/z/n) x 256 units; weights = 32 named uint4 = 128 VGPR/thread at 512 thr.
// Sync per step: r,z halves publish -> n halves combine, publish h -> all reload h.
// Flags are step-tagged (==s+1 exact match): 0xAA poison / stale values never match.
#define DECLW(j) uint4 wq_##j = Wp2[wbase + (size_t)(j)*512];
#define PINW(j)  asm volatile("" : "+v"(wq_##j.x), "+v"(wq_##j.y), "+v"(wq_##j.z), "+v"(wq_##j.w));
#define DOTW(j, A) { uint4 hv = *(const uint4*)&hq[ch*128 + (j)*4]; \
  A = dot2(wq_##j.x, hv.x, A); A = dot2(wq_##j.y, hv.y, A); \
  A = dot2(wq_##j.z, hv.z, A); A = dot2(wq_##j.w, hv.w, A); }

#define SCANWAIT(fp, v) \
  while (__hip_atomic_load((fp), __ATOMIC_ACQUIRE, __HIP_MEMORY_SCOPE_AGENT) != (v)) \
    __builtin_amdgcn_s_sleep(1);

__global__ __launch_bounds__(512, 2) void gru_scan6(
    const uint4* __restrict__ Wp2, const __half* __restrict__ gi_c,
    const float* __restrict__ bhh, __half* __restrict__ ys_c,
    float* __restrict__ hstate, unsigned* __restrict__ xch,
    unsigned* __restrict__ flags, int CH, int first) {
  int wg = blockIdx.x;
  int b = wg & 31;
  int role = wg >> 5;          // 0,1=r halves; 2,3=z; 4,5=n
  int g = role >> 1, hh = role & 1;
  int i = threadIdx.x;
  int u = i & 255, ch = i >> 8;
  int ug = hh*256 + u;

  __shared__ unsigned hq[256];       // h as packed f16x2
  __shared__ float part[256];
  __shared__ __half sval[256];
  __shared__ unsigned rzst[2][128];

  size_t wbase = (size_t)((g*2 + hh)*32)*512 + i;
  DECLW(0)  DECLW(1)  DECLW(2)  DECLW(3)  DECLW(4)  DECLW(5)  DECLW(6)  DECLW(7)
  DECLW(8)  DECLW(9)  DECLW(10) DECLW(11) DECLW(12) DECLW(13) DECLW(14) DECLW(15)
  DECLW(16) DECLW(17) DECLW(18) DECLW(19) DECLW(20) DECLW(21) DECLW(22) DECLW(23)
  DECLW(24) DECLW(25) DECLW(26) DECLW(27) DECLW(28) DECLW(29) DECLW(30) DECLW(31)
  PINW(0)  PINW(1)  PINW(2)  PINW(3)  PINW(4)  PINW(5)  PINW(6)  PINW(7)
  PINW(8)  PINW(9)  PINW(10) PINW(11) PINW(12) PINW(13) PINW(14) PINW(15)
  PINW(16) PINW(17) PINW(18) PINW(19) PINW(20) PINW(21) PINW(22) PINW(23)
  PINW(24) PINW(25) PINW(26) PINW(27) PINW(28) PINW(29) PINW(30) PINW(31)

  float bias = 0.f;
  if (!ch) bias = bhh[g*512 + ug];

  if (i < 256) {
    hq[i] = first ? 0u : pack2(hstate[b*512 + 2*i], hstate[b*512 + 2*i + 1]);
  }
  __syncthreads();

  const __half* gib = gi_c + (size_t)b*CH*1536 + g*512 + ug;
  __half* ysb = ys_c + (size_t)b*CH*512;
  unsigned* flg = flags + b*12;                 // [role][parity]
  unsigned* xb  = xch + (size_t)b*2*3*256;      // [parity][slot r/z/h][256]

  for (int s = 0; s < CH; ++s) {
    int p = s & 1;
    float giv = 0.f;
    if (!ch) giv = (float)gib[(size_t)s*1536];
    float a0 = 0.f, a1 = 0.f, a2 = 0.f, a3 = 0.f;
    DOTW(0,a0)  DOTW(1,a1)  DOTW(2,a2)  DOTW(3,a3)
    DOTW(4,a0)  DOTW(5,a1)  DOTW(6,a2)  DOTW(7,a3)
    DOTW(8,a0)  DOTW(9,a1)  DOTW(10,a2) DOTW(11,a3)
    DOTW(12,a0) DOTW(13,a1) DOTW(14,a2) DOTW(15,a3)
    DOTW(16,a0) DOTW(17,a1) DOTW(18,a2) DOTW(19,a3)
    DOTW(20,a0) DOTW(21,a1) DOTW(22,a2) DOTW(23,a3)
    DOTW(24,a0) DOTW(25,a1) DOTW(26,a2) DOTW(27,a3)
    DOTW(28,a0) DOTW(29,a1) DOTW(30,a2) DOTW(31,a3)
    float a = (a0 + a1) + (a2 + a3);
    if (ch) part[u] = a;
    __syncthreads();
    unsigned* xp = xb + p*3*256;

    if (role < 4) {
      if (!ch) {
        float tot = a + part[u] + bias;
        sval[u] = (__half)sigmoidf_(giv + tot);
      }
      __syncthreads();
      if (i < 128)
        __hip_atomic_store(&xp[g*256 + hh*128 + i], pack2h(sval[2*i], sval[2*i+1]),
                           __ATOMIC_RELAXED, __HIP_MEMORY_SCOPE_AGENT);
      __syncthreads();   // drains vmcnt(0) for all waves before flag release
      if (i == 0)
        __hip_atomic_store(&flg[role*2 + p], (unsigned)(s + 1),
                           __ATOMIC_RELEASE, __HIP_MEMORY_SCOPE_AGENT);
    } else {
      float tot = 0.f;
      if (!ch) tot = a + part[u] + bias;       // W_n.h + b_n for unit ug
      if (i == 0) {
        SCANWAIT(&flg[hh*2 + p], (unsigned)(s + 1));        // r half
        SCANWAIT(&flg[(2 + hh)*2 + p], (unsigned)(s + 1));  // z half
      }
      __syncthreads();
      if (i < 128) {
        rzst[0][i] = __hip_atomic_load(&xp[0*256 + hh*128 + i],
                                       __ATOMIC_RELAXED, __HIP_MEMORY_SCOPE_AGENT);
        rzst[1][i] = __hip_atomic_load(&xp[1*256 + hh*128 + i],
                                       __ATOMIC_RELAXED, __HIP_MEMORY_SCOPE_AGENT);
      }
      __syncthreads();
      if (!ch) {
        float r = hsel(rzst[0][u >> 1], u & 1);
        float z = hsel(rzst[1][u >> 1], u & 1);
        float hn = tanhf_(giv + r*tot);
        float ho = hsel(hq[ug >> 1], ug & 1);
        float hnew = (1.f - z)*hn + z*ho;
        ysb[(size_t)s*512 + ug] = (__half)hnew;
        sval[u] = (__half)hnew;
        if (s == CH - 1) hstate[b*512 + ug] = hnew;
      }
      __syncthreads();
      if (i < 128)
        __hip_atomic_store(&xp[2*256 + hh*128 + i], pack2h(sval[2*i], sval[2*i+1]),
                           __ATOMIC_RELAXED, __HIP_MEMORY_SCOPE_AGENT);
      __syncthreads();
      if (i == 0)
        __hip_atomic_store(&flg[role*2 + p], (unsigned)(s + 1),
                           __ATOMIC_RELEASE, __HIP_MEMORY_SCOPE_AGENT);
    }

    // everyone: wait for both h halves, reload h
    if (i == 0) {
      SCANWAIT(&flg[4*2 + p], (unsigned)(s + 1));
      SCANWAIT(&flg[5*2 + p], (unsigned)(s + 1));
    }
    __syncthreads();
    if (i < 256)
      hq[i] = __hip_atomic_load(&xp[2*256 + i],
                                __ATOMIC_RELAXED, __HIP_MEMORY_SCOPE_AGENT);
    __syncthreads();
  }
}

// ---------------- launch ----------------
extern "C" void kernel_launch(void* const* d_in, const int* in_sizes, int n_in,
                              void* d_out, int out_size, void* d_ws, size_t ws_size,
                              hipStream_t stream) {
  const float* f0     = (const float*)d_in[0];
  const float* loud   = (const float*)d_in[1];
  const float* es     = (const float*)d_in[2];
  const float* preW   = (const float*)d_in[3];
  const float* preb   = (const float*)d_in[4];
  const float* Wih    = (const float*)d_in[5];
  const float* Whh    = (const float*)d_in[6];
  const float* b_ih   = (const float*)d_in[7];
  const float* b_hh   = (const float*)d_in[8];
  const float* postW  = (const float*)d_in[9];
  const float* postb  = (const float*)d_in[10];
  const float* harmW  = (const float*)d_in[11];
  const float* harmb  = (const float*)d_in[12];
  const float* noiseW = (const float*)d_in[13];
  const float* noiseb = (const float*)d_in[14];
  const float* hypW1  = (const float*)d_in[15];
  const float* hypb1  = (const float*)d_in[16];
  const float* Wdh    = (const float*)d_in[17];
  const float* bdh    = (const float*)d_in[18];
  const float* Wbh    = (const float*)d_in[19];
  const float* bbh    = (const float*)d_in[20];
  const float* Wdn    = (const float*)d_in[21];
  const float* bdn    = (const float*)d_in[22];
  const float* Wbn    = (const float*)d_in[23];
  const float* bbn    = (const float*)d_in[24];
  (void)in_sizes; (void)n_in; (void)out_size;

  const size_t FIXED = 12288ull*1024ull;
  int CH = 20;
  {
    const int opts[8] = {2000, 1000, 500, 400, 200, 100, 40, 20};
    for (int i = 0; i < 8; ++i) {
      size_t need = FIXED + (size_t)opts[i] * 163840ull + 65536ull;
      if (need <= ws_size) { CH = opts[i]; break; }
    }
  }
  const int NC = T_ / CH;
  const int Mc = B_ * CH;

  char* w = (char*)d_ws;
  size_t off = 0;
  auto alloc = [&](size_t bytes) -> void* {
    void* p = (void*)(w + off);
    off += (bytes + 255) & ~(size_t)255;
    return p;
  };
  float*    hE      = (float*)alloc((size_t)32*256*4);
  float*    effb    = (float*)alloc((size_t)32*256*4);
  float*    hstate  = (float*)alloc((size_t)32*512*4);
  __half*   effW    = (__half*)alloc((size_t)32*256*512*2);
  __half*   Wih16   = (__half*)alloc((size_t)1536*512*2);
  __half*   postW16 = (__half*)alloc((size_t)512*512*2);
  uint4*    Wp2     = (uint4*)alloc((size_t)3*2*32*512*16);
  unsigned* xch     = (unsigned*)alloc((size_t)32*2*3*256*4);
  unsigned* flags   = (unsigned*)alloc((size_t)32*12*4);
  __half*   xpre    = (__half*)alloc((size_t)Mc*512*2);
  __half*   gibuf   = (__half*)alloc((size_t)Mc*1536*2);
  __half*   ysbuf   = (__half*)alloc((size_t)Mc*512*2);
  __half*   postc   = xpre;   // xpre dead after gi GEMM

  hyper1<<<32, 256, 0, stream>>>(es, hypW1, hypb1, hE);
  hyper2<<<32, 256, 0, stream>>>(hE, Wbh, bbh, harmb, Wbn, bbn, noiseb, effb);
  hyper3<<<200, 256, 0, stream>>>(hE, Wdh, bdh, harmW, effW, 0);
  hyper3<<<130, 256, 0, stream>>>(hE, Wdn, bdn, noiseW, effW, NH_);
  cvt_f16<<<(1536*512)/256, 256, 0, stream>>>(Wih, Wih16, 1536*512);
  cvt_f16<<<(512*512)/256, 256, 0, stream>>>(postW, postW16, 512*512);
  pack_whh2<<<384, 256, 0, stream>>>(Whh, Wp2);

  for (int c = 0; c < NC; ++c) {
    int c0 = c * CH;
    pre_kernel<<<dim3(CH*2, 32), 256, 0, stream>>>(f0, loud, preW, preb, xpre, CH, c0);
    gemm_nt<0><<<dim3(Mc/128, 12), 256, 0, stream>>>(xpre, Wih16, gibuf, b_ih, 1536);
    gru_scan6<<<192, 512, 0, stream>>>(Wp2, gibuf, b_hh, ysbuf, hstate, xch, flags,
                                       CH, c == 0 ? 1 : 0);
    gemm_nt<1><<<dim3(Mc/128, 4), 256, 0, stream>>>(ysbuf, postW16, postc, postb, 512);
    heads_gemm<<<dim3((CH+127)/128, 2, 32), 256, 0, stream>>>(postc, effW, effb,
                                                              (float*)d_out, CH, c0);
  }
}

// Round 6
// 5988.665 us; speedup vs baseline: 11.9333x; 4.1878x over previous
//
#include <hip/hip_runtime.h>
#include <hip/hip_fp16.h>
#include <stdint.h>

#define B_  32
#define T_  2000
#define H_  512
#define NH_ 100
#define NM_ 65

typedef _Float16 f16x8 __attribute__((ext_vector_type(8)));
typedef _Float16 f16x2 __attribute__((ext_vector_type(2)));
typedef float    f32x4 __attribute__((ext_vector_type(4)));

typedef __attribute__((address_space(3))) void lds_void_t;
typedef __attribute__((address_space(1))) void glb_void_t;

__device__ __forceinline__ void gload_lds16(const void* g, void* l) {
  __builtin_amdgcn_global_load_lds((const glb_void_t*)g, (lds_void_t*)l, 16, 0, 0);
}

__device__ __forceinline__ float sigmoidf_(float x) {
  float e = __builtin_amdgcn_exp2f(-x * 1.44269504f);
  return __builtin_amdgcn_rcpf(1.0f + e);
}
__device__ __forceinline__ float tanhf_(float x) {
  float e = __builtin_amdgcn_exp2f(x * 2.88539008f);
  return 1.0f - 2.0f * __builtin_amdgcn_rcpf(e + 1.0f);
}
__device__ __forceinline__ float dot2(unsigned w, unsigned h, float acc) {
  return __builtin_amdgcn_fdot2(__builtin_bit_cast(f16x2, w),
                                __builtin_bit_cast(f16x2, h), acc, false);
}
__device__ __forceinline__ unsigned pack2(float a, float b) {
  __half2 h = __floats2half2_rn(a, b);
  return __builtin_bit_cast(unsigned, h);
}
__device__ __forceinline__ float hsel(unsigned w, int hi) {
  __half2 h2 = __builtin_bit_cast(__half2, w);
  return hi ? __high2float(h2) : __low2float(h2);
}

// ---------------- hypernetwork ----------------
__global__ void hyper1(const float* __restrict__ es, const float* __restrict__ W1,
                       const float* __restrict__ b1, float* __restrict__ hE) {
  int b = blockIdx.x, o = threadIdx.x;   // 32 x 256
  float a = b1[o];
  #pragma unroll
  for (int c = 0; c < 16; ++c) a += es[b*16 + c] * W1[o*16 + c];
  hE[b*256 + o] = fmaxf(a, 0.f);
}

__global__ void hyper2(const float* __restrict__ hE,
                       const float* __restrict__ Wbh, const float* __restrict__ bbh,
                       const float* __restrict__ harmb,
                       const float* __restrict__ Wbn, const float* __restrict__ bbn,
                       const float* __restrict__ noiseb, float* __restrict__ effb) {
  int b = blockIdx.x, o = threadIdx.x;
  if (o < NH_) {
    float a = bbh[o] + harmb[o];
    for (int c = 0; c < 256; ++c) a += hE[b*256 + c] * Wbh[o*256 + c];
    effb[b*256 + o] = a;
  } else if (o < NH_ + NM_) {
    int q = o - NH_;
    float a = bbn[q] + noiseb[q];
    for (int c = 0; c < 256; ++c) a += hE[b*256 + c] * Wbn[q*256 + c];
    effb[b*256 + o] = a;
  }
}

// effW[b][o_base+o][h] = baseW[o*512+h] + bd[row] + sum_c Wd[row][c]*hE[b][c]
__global__ __launch_bounds__(256) void hyper3(
    const float* __restrict__ hE, const float* __restrict__ Wd,
    const float* __restrict__ bd, const float* __restrict__ baseW,
    __half* __restrict__ effW, int o_base) {
  __shared__ float wl[256*33];
  __shared__ float hEl[32*256];
  int tid = threadIdx.x;
  int row0 = blockIdx.x * 256;
  #pragma unroll
  for (int i = 0; i < 32; ++i) hEl[i*256 + tid] = hE[i*256 + tid];
  float acc[32];
  #pragma unroll
  for (int b = 0; b < 32; ++b) acc[b] = 0.f;
  for (int cc = 0; cc < 256; cc += 32) {
    __syncthreads();
    #pragma unroll
    for (int i = 0; i < 32; ++i) {
      int idx = i*256 + tid;
      int r = idx >> 5, c = idx & 31;
      wl[r*33 + c] = Wd[(size_t)(row0 + r)*256 + cc + c];
    }
    __syncthreads();
    #pragma unroll
    for (int c = 0; c < 32; ++c) {
      float w = wl[tid*33 + c];
      #pragma unroll
      for (int b = 0; b < 32; ++b) acc[b] += w * hEl[b*256 + cc + c];
    }
  }
  int row = row0 + tid;
  int o = row >> 9, h = row & 511;
  float base = baseW[row] + bd[row];
  #pragma unroll
  for (int b = 0; b < 32; ++b) {
    effW[((size_t)b*256 + o_base + o)*512 + h] = (__half)(acc[b] + base);
  }
}

// ---------------- converts ----------------
__global__ void cvt_f16(const float* __restrict__ in, __half* __restrict__ out, int n) {
  int i = blockIdx.x*256 + threadIdx.x;
  if (i < n) out[i] = (__half)in[i];
}

// Wp3[(w*32 + k)*384 + t]: WG w (unit-block), thread t (rr=t>>1 row, ch=t&1 col-half),
// k-th 8-col quad. row = g*512 + w*64 + j (g=rr>>6, j=rr&63), cols = ch*256 + k*8 ..+8
__global__ void pack_whh3(const float* __restrict__ Whh, uint4* __restrict__ Wp3) {
  int idx = blockIdx.x*256 + threadIdx.x;    // 8*32*384 = 98304
  int t = idx % 384;
  int k = (idx / 384) & 31;
  int w = idx / (384*32);
  int rr = t >> 1, ch = t & 1;
  int g = rr >> 6, j = rr & 63;
  int row = g*512 + w*64 + j;
  int col0 = ch*256 + k*8;
  const float* src = Whh + (size_t)row*512 + col0;
  uint4 o;
  o.x = pack2(src[0], src[1]);
  o.y = pack2(src[2], src[3]);
  o.z = pack2(src[4], src[5]);
  o.w = pack2(src[6], src[7]);
  Wp3[idx] = o;
}

// ---------------- pre layer (per chunk) ----------------
__global__ void pre_kernel(const float* __restrict__ f0, const float* __restrict__ loud,
                           const float* __restrict__ preW, const float* __restrict__ preb,
                           __half* __restrict__ xpre, int CH, int c0) {
  int b = blockIdx.y;
  int idx = blockIdx.x*256 + threadIdx.x;    // CH*512
  int t = idx >> 9, h = idx & 511;
  int mg = b*T_ + c0 + t;
  float v = f0[mg]*preW[h*2+0] + loud[mg]*preW[h*2+1] + preb[h];
  v = v >= 0.f ? v : 0.01f*v;
  xpre[((size_t)b*CH + t)*512 + h] = (__half)v;
}

// ---------------- trunk GEMM (NT, K=512, 128x128 tile, f16 MFMA) ----------------
template<int ACT>
__global__ __launch_bounds__(256) void gemm_nt(
    const __half* __restrict__ A, const __half* __restrict__ B,
    __half* __restrict__ C, const float* __restrict__ bias, int N) {
  constexpr int K = 512;
  __shared__ __align__(16) __half As[128*64];
  __shared__ __align__(16) __half Bs[128*64];
  int tid = threadIdx.x;
  int bx = blockIdx.x, by = blockIdx.y;
  const __half* Ab = A + (size_t)bx*128*K;
  const __half* Bb = B + (size_t)by*128*K;
  f32x4 acc[4][4] = {};
  int lane = tid & 63;
  int wv = tid >> 6, wr = wv >> 1, wc = wv & 1;
  int lr = lane & 15, lk = lane >> 4;

  for (int kt = 0; kt < K/64; ++kt) {
    #pragma unroll
    for (int j = 0; j < 4; ++j) {
      int idx = j*256 + tid;
      int row = idx >> 3, seg = idx & 7;
      const __half* gpA = Ab + (size_t)row*K + kt*64 + seg*8;
      const __half* gpB = Bb + (size_t)row*K + kt*64 + seg*8;
      __half* lpA = As + (size_t)(j*256 + (tid & ~63))*8;
      __half* lpB = Bs + (size_t)(j*256 + (tid & ~63))*8;
      gload_lds16(gpA, lpA);
      gload_lds16(gpB, lpB);
    }
    __syncthreads();
    #pragma unroll
    for (int ks = 0; ks < 2; ++ks) {
      f16x8 af[4], bf[4];
      #pragma unroll
      for (int i = 0; i < 4; ++i)
        af[i] = *(const f16x8*)(As + (wr*64 + i*16 + lr)*64 + ks*32 + lk*8);
      #pragma unroll
      for (int j2 = 0; j2 < 4; ++j2)
        bf[j2] = *(const f16x8*)(Bs + (wc*64 + j2*16 + lr)*64 + ks*32 + lk*8);
      #pragma unroll
      for (int i = 0; i < 4; ++i)
        #pragma unroll
        for (int j2 = 0; j2 < 4; ++j2)
          acc[i][j2] = __builtin_amdgcn_mfma_f32_16x16x32_f16(af[i], bf[j2], acc[i][j2], 0, 0, 0);
    }
    __syncthreads();
  }

  #pragma unroll
  for (int j2 = 0; j2 < 4; ++j2) {
    int col = by*128 + wc*64 + j2*16 + lr;
    float bv = bias[col];
    #pragma unroll
    for (int i = 0; i < 4; ++i) {
      int row0 = bx*128 + wr*64 + i*16 + lk*4;
      #pragma unroll
      for (int r = 0; r < 4; ++r) {
        float v = acc[i][j2][r] + bv;
        if (ACT == 1) v = v >= 0.f ? v : 0.01f*v;
        C[(size_t)(row0 + r)*N + col] = (__half)v;
      }
    }
  }
}

// ---------------- heads GEMM: per-batch modulated weights, sigmoid, fp32 out ----------------
__global__ __launch_bounds__(256) void heads_gemm(
    const __half* __restrict__ Apc, const __half* __restrict__ effW,
    const float* __restrict__ effb, float* __restrict__ out, int CH, int c0) {
  constexpr int K = 512;
  __shared__ __align__(16) __half As[128*64];
  __shared__ __align__(16) __half Bs[128*64];
  int tid = threadIdx.x;
  int bx = blockIdx.x, by = blockIdx.y, b = blockIdx.z;
  const __half* Ab = Apc + (size_t)b*CH*K;
  const __half* Bb = effW + ((size_t)b*256 + (size_t)by*128)*K;
  f32x4 acc[4][4] = {};
  int lane = tid & 63;
  int wv = tid >> 6, wr = wv >> 1, wc = wv & 1;
  int lr = lane & 15, lk = lane >> 4;

  for (int kt = 0; kt < K/64; ++kt) {
    #pragma unroll
    for (int j = 0; j < 4; ++j) {
      int idx = j*256 + tid;
      int row = idx >> 3, seg = idx & 7;
      int ar = bx*128 + row; if (ar > CH-1) ar = CH-1;
      const __half* gpA = Ab + (size_t)ar*K + kt*64 + seg*8;
      const __half* gpB = Bb + (size_t)row*K + kt*64 + seg*8;
      __half* lpA = As + (size_t)(j*256 + (tid & ~63))*8;
      __half* lpB = Bs + (size_t)(j*256 + (tid & ~63))*8;
      gload_lds16(gpA, lpA);
      gload_lds16(gpB, lpB);
    }
    __syncthreads();
    #pragma unroll
    for (int ks = 0; ks < 2; ++ks) {
      f16x8 af[4], bf[4];
      #pragma unroll
      for (int i = 0; i < 4; ++i)
        af[i] = *(const f16x8*)(As + (wr*64 + i*16 + lr)*64 + ks*32 + lk*8);
      #pragma unroll
      for (int j2 = 0; j2 < 4; ++j2)
        bf[j2] = *(const f16x8*)(Bs + (wc*64 + j2*16 + lr)*64 + ks*32 + lk*8);
      #pragma unroll
      for (int i = 0; i < 4; ++i)
        #pragma unroll
        for (int j2 = 0; j2 < 4; ++j2)
          acc[i][j2] = __builtin_amdgcn_mfma_f32_16x16x32_f16(af[i], bf[j2], acc[i][j2], 0, 0, 0);
    }
    __syncthreads();
  }

  #pragma unroll
  for (int j2 = 0; j2 < 4; ++j2) {
    int o = by*128 + wc*64 + j2*16 + lr;
    if (o < NH_ + NM_) {
      float bv = effb[b*256 + o];
      #pragma unroll
      for (int i = 0; i < 4; ++i) {
        #pragma unroll
        for (int r = 0; r < 4; ++r) {
          int trow = bx*128 + wr*64 + i*16 + lk*4 + r;
          if (trow < CH) {
            int tg = c0 + trow;
            float v = sigmoidf_(acc[i][j2][r] + bv);
            if (o < NH_)
              out[((size_t)b*T_ + tg)*NH_ + o] = v;
            else
              out[(size_t)B_*T_*NH_ + ((size_t)b*T_ + tg)*NM_ + (o - NH_)] = v;
          }
        }
      }
    }
  }
}

// ---------------- GRU scan: 8 WGs/batch (unit-partition), 1 exchange hop/step ----
// W_hh (1.57 MB f16) > 512 KB/CU register file -> split across 8 CUs per batch:
// WG owns 64 units x 3 gates = 192 KB = 128 VGPR on 384 threads. Weights loaded via
// inline-asm global_load_dwordx4: asm outputs are NOT rematerializable, so the
// allocator cannot sink the loads back into the loop (round-5 failure: VGPR=84,
// weights re-streamed from L2 every step). Combine r,z,n locally -> publish only
// h-slice. All cross-WG data via RELAXED agent atomics (LLC-direct, no L1/L2
// residency) ordered by vmcnt(0)+barrier before a RELAXED step-tagged flag:
// avoids release/acquire L2 writeback/invalidate storms. Exact-match tags (s+1)
// are safe vs 0xAA poison and stale values (monotone fresh overwrites).
#define LOADW(k) { const uint4* p = Wp3 + ((size_t)(w*32 + (k)))*384 + t; \
  asm volatile("global_load_dwordx4 %0, %1, off" : "=v"(wq_##k) : "v"(p) : "memory"); }

#define DOTW(k, A) { uint4 hv = *(const uint4*)&hq[ch*128 + (k)*4]; \
  A = dot2(wq_##k.x, hv.x, A); A = dot2(wq_##k.y, hv.y, A); \
  A = dot2(wq_##k.z, hv.z, A); A = dot2(wq_##k.w, hv.w, A); }

__global__ __launch_bounds__(512) __attribute__((amdgpu_waves_per_eu(2, 4)))
void gru_scan8(
    const uint4* __restrict__ Wp3, const __half* __restrict__ gi_c,
    const float* __restrict__ bhh, __half* __restrict__ ys_c,
    float* __restrict__ hstate, unsigned* __restrict__ xch,
    unsigned* __restrict__ flags, int CH, int first) {
  int wg = blockIdx.x;
  int b = wg & 31;            // batch
  int w = wg >> 5;            // unit-block 0..7 (units w*64 .. +64)
  int t = threadIdx.x;
  int rr = t >> 1, ch = t & 1;
  bool wact = (t < 384);      // waves 0-5 hold weights

  __shared__ __align__(16) unsigned hq[256];   // full h as packed f16x2
  __shared__ float part[384];                  // [row 0..191][colhalf]
  __shared__ float gil[192];                   // gi slices for combine

  uint4 wq_0{},wq_1{},wq_2{},wq_3{},wq_4{},wq_5{},wq_6{},wq_7{},
        wq_8{},wq_9{},wq_10{},wq_11{},wq_12{},wq_13{},wq_14{},wq_15{},
        wq_16{},wq_17{},wq_18{},wq_19{},wq_20{},wq_21{},wq_22{},wq_23{},
        wq_24{},wq_25{},wq_26{},wq_27{},wq_28{},wq_29{},wq_30{},wq_31{};
  if (wact) {
    LOADW(0)  LOADW(1)  LOADW(2)  LOADW(3)  LOADW(4)  LOADW(5)  LOADW(6)  LOADW(7)
    LOADW(8)  LOADW(9)  LOADW(10) LOADW(11) LOADW(12) LOADW(13) LOADW(14) LOADW(15)
    LOADW(16) LOADW(17) LOADW(18) LOADW(19) LOADW(20) LOADW(21) LOADW(22) LOADW(23)
    LOADW(24) LOADW(25) LOADW(26) LOADW(27) LOADW(28) LOADW(29) LOADW(30) LOADW(31)
  }
  asm volatile("s_waitcnt vmcnt(0)" ::: "memory");
  __builtin_amdgcn_sched_barrier(0);

  // combine-thread biases (t<32 handles units 2t, 2t+1)
  float br0=0.f,br1=0.f,bz0=0.f,bz1=0.f,bn0=0.f,bn1=0.f;
  if (t < 32) {
    int u0 = w*64 + 2*t;
    br0 = bhh[u0];        br1 = bhh[u0+1];
    bz0 = bhh[512+u0];    bz1 = bhh[512+u0+1];
    bn0 = bhh[1024+u0];   bn1 = bhh[1024+u0+1];
  }

  if (t < 256)
    hq[t] = first ? 0u : pack2(hstate[b*512 + 2*t], hstate[b*512 + 2*t + 1]);
  __syncthreads();

  const __half* gib = gi_c + (size_t)b*CH*1536;
  __half* ysb = ys_c + (size_t)b*CH*512;
  unsigned* flg = flags + (size_t)b*8;                 // + p*256 parity offset
  unsigned* xb  = xch + (size_t)b*8*32;                // + p*8192 parity offset

  for (int s = 0; s < CH; ++s) {
    int p = s & 1;
    // gi for the combine (3 gates x own 64 units), issued early, consumed post-gemv
    float giv = 0.f;
    if (t < 192) giv = (float)gib[(size_t)s*1536 + (t >> 6)*512 + w*64 + (t & 63)];

    if (wact) {
      float a0 = 0.f, a1 = 0.f, a2 = 0.f, a3 = 0.f;
      DOTW(0,a0)  DOTW(1,a1)  DOTW(2,a2)  DOTW(3,a3)
      DOTW(4,a0)  DOTW(5,a1)  DOTW(6,a2)  DOTW(7,a3)
      DOTW(8,a0)  DOTW(9,a1)  DOTW(10,a2) DOTW(11,a3)
      DOTW(12,a0) DOTW(13,a1) DOTW(14,a2) DOTW(15,a3)
      DOTW(16,a0) DOTW(17,a1) DOTW(18,a2) DOTW(19,a3)
      DOTW(20,a0) DOTW(21,a1) DOTW(22,a2) DOTW(23,a3)
      DOTW(24,a0) DOTW(25,a1) DOTW(26,a2) DOTW(27,a3)
      DOTW(28,a0) DOTW(29,a1) DOTW(30,a2) DOTW(31,a3)
      part[rr*2 + ch] = (a0 + a1) + (a2 + a3);
      if (t < 192) gil[t] = giv;
    }
    __syncthreads();

    unsigned* xp  = xb  + (size_t)p*8192;
    unsigned* flp = flg + (size_t)p*256;

    if (t < 32) {
      int j0 = 2*t, j1 = 2*t + 1;
      float ghr0 = part[j0*2] + part[j0*2+1] + br0;
      float ghr1 = part[j1*2] + part[j1*2+1] + br1;
      float ghz0 = part[(64+j0)*2] + part[(64+j0)*2+1] + bz0;
      float ghz1 = part[(64+j1)*2] + part[(64+j1)*2+1] + bz1;
      float ghn0 = part[(128+j0)*2] + part[(128+j0)*2+1] + bn0;
      float ghn1 = part[(128+j1)*2] + part[(128+j1)*2+1] + bn1;
      float r0 = sigmoidf_(gil[j0] + ghr0);
      float r1 = sigmoidf_(gil[j1] + ghr1);
      float z0 = sigmoidf_(gil[64+j0] + ghz0);
      float z1 = sigmoidf_(gil[64+j1] + ghz1);
      float n0 = tanhf_(gil[128+j0] + r0*ghn0);
      float n1 = tanhf_(gil[128+j1] + r1*ghn1);
      unsigned hold = hq[w*32 + t];
      float h0 = (1.f - z0)*n0 + z0*hsel(hold, 0);
      float h1 = (1.f - z1)*n1 + z1*hsel(hold, 1);
      unsigned hv = pack2(h0, h1);
      *(unsigned*)&ysb[(size_t)s*512 + w*64 + j0] = hv;            // ys (f16 pair)
      __hip_atomic_store(&xp[w*32 + t], hv,
                         __ATOMIC_RELAXED, __HIP_MEMORY_SCOPE_AGENT);
      if (s == CH - 1) {
        hstate[b*512 + w*64 + j0] = h0;
        hstate[b*512 + w*64 + j1] = h1;
      }
    }
    asm volatile("s_waitcnt vmcnt(0)" ::: "memory");   // data acked at LLC
    __syncthreads();
    if (t == 0)
      __hip_atomic_store(&flp[w], (unsigned)(s + 1),
                         __ATOMIC_RELAXED, __HIP_MEMORY_SCOPE_AGENT);
    if (t < 8) {
      while (__hip_atomic_load(&flp[t], __ATOMIC_RELAXED, __HIP_MEMORY_SCOPE_AGENT)
             != (unsigned)(s + 1))
        __builtin_amdgcn_s_sleep(2);
    }
    __syncthreads();
    if (t < 256)
      hq[t] = __hip_atomic_load(&xp[t], __ATOMIC_RELAXED, __HIP_MEMORY_SCOPE_AGENT);
    __syncthreads();
  }
}

// ---------------- launch ----------------
extern "C" void kernel_launch(void* const* d_in, const int* in_sizes, int n_in,
                              void* d_out, int out_size, void* d_ws, size_t ws_size,
                              hipStream_t stream) {
  const float* f0     = (const float*)d_in[0];
  const float* loud   = (const float*)d_in[1];
  const float* es     = (const float*)d_in[2];
  const float* preW   = (const float*)d_in[3];
  const float* preb   = (const float*)d_in[4];
  const float* Wih    = (const float*)d_in[5];
  const float* Whh    = (const float*)d_in[6];
  const float* b_ih   = (const float*)d_in[7];
  const float* b_hh   = (const float*)d_in[8];
  const float* postW  = (const float*)d_in[9];
  const float* postb  = (const float*)d_in[10];
  const float* harmW  = (const float*)d_in[11];
  const float* harmb  = (const float*)d_in[12];
  const float* noiseW = (const float*)d_in[13];
  const float* noiseb = (const float*)d_in[14];
  const float* hypW1  = (const float*)d_in[15];
  const float* hypb1  = (const float*)d_in[16];
  const float* Wdh    = (const float*)d_in[17];
  const float* bdh    = (const float*)d_in[18];
  const float* Wbh    = (const float*)d_in[19];
  const float* bbh    = (const float*)d_in[20];
  const float* Wdn    = (const float*)d_in[21];
  const float* bdn    = (const float*)d_in[22];
  const float* Wbn    = (const float*)d_in[23];
  const float* bbn    = (const float*)d_in[24];
  (void)in_sizes; (void)n_in; (void)out_size;

  const size_t FIXED = 13312ull*1024ull;   // ~13 MB fixed region
  int CH = 20;
  {
    const int opts[8] = {2000, 1000, 500, 400, 200, 100, 40, 20};
    for (int i = 0; i < 8; ++i) {
      size_t need = FIXED + (size_t)opts[i] * 163840ull + 65536ull;
      if (need <= ws_size) { CH = opts[i]; break; }
    }
  }
  const int NC = T_ / CH;
  const int Mc = B_ * CH;

  char* w = (char*)d_ws;
  size_t off = 0;
  auto alloc = [&](size_t bytes) -> void* {
    void* p = (void*)(w + off);
    off += (bytes + 255) & ~(size_t)255;
    return p;
  };
  float*    hE      = (float*)alloc((size_t)32*256*4);
  float*    effb    = (float*)alloc((size_t)32*256*4);
  float*    hstate  = (float*)alloc((size_t)32*512*4);
  __half*   effW    = (__half*)alloc((size_t)32*256*512*2);
  __half*   Wih16   = (__half*)alloc((size_t)1536*512*2);
  __half*   postW16 = (__half*)alloc((size_t)512*512*2);
  uint4*    Wp3     = (uint4*)alloc((size_t)8*32*384*16 + 4096);
  unsigned* xch     = (unsigned*)alloc((size_t)2*32*8*32*4);    // [p][b][w][32]
  unsigned* flags   = (unsigned*)alloc((size_t)2*32*8*4 + 256); // [p? via +p*256]
  __half*   xpre    = (__half*)alloc((size_t)Mc*512*2);
  __half*   gibuf   = (__half*)alloc((size_t)Mc*1536*2);
  __half*   ysbuf   = (__half*)alloc((size_t)Mc*512*2);
  __half*   postc   = xpre;   // xpre dead after gi GEMM

  hyper1<<<32, 256, 0, stream>>>(es, hypW1, hypb1, hE);
  hyper2<<<32, 256, 0, stream>>>(hE, Wbh, bbh, harmb, Wbn, bbn, noiseb, effb);
  hyper3<<<200, 256, 0, stream>>>(hE, Wdh, bdh, harmW, effW, 0);
  hyper3<<<130, 256, 0, stream>>>(hE, Wdn, bdn, noiseW, effW, NH_);
  cvt_f16<<<(1536*512)/256, 256, 0, stream>>>(Wih, Wih16, 1536*512);
  cvt_f16<<<(512*512)/256, 256, 0, stream>>>(postW, postW16, 512*512);
  pack_whh3<<<384, 256, 0, stream>>>(Whh, Wp3);

  for (int c = 0; c < NC; ++c) {
    int c0 = c * CH;
    pre_kernel<<<dim3(CH*2, 32), 256, 0, stream>>>(f0, loud, preW, preb, xpre, CH, c0);
    gemm_nt<0><<<dim3(Mc/128, 12), 256, 0, stream>>>(xpre, Wih16, gibuf, b_ih, 1536);
    gru_scan8<<<256, 512, 0, stream>>>(Wp3, gibuf, b_hh, ysbuf, hstate, xch, flags,
                                       CH, c == 0 ? 1 : 0);
    gemm_nt<1><<<dim3(Mc/128, 4), 256, 0, stream>>>(ysbuf, postW16, postc, postb, 512);
    heads_gemm<<<dim3((CH+127)/128, 2, 32), 256, 0, stream>>>(postc, effW, effb,
                                                              (float*)d_out, CH, c0);
  }
}

// Round 7
// 4512.051 us; speedup vs baseline: 15.8386x; 1.3273x over previous
//
#include <hip/hip_runtime.h>
#include <hip/hip_fp16.h>
#include <stdint.h>

#define B_  32
#define T_  2000
#define H_  512
#define NH_ 100
#define NM_ 65

typedef _Float16 f16x8 __attribute__((ext_vector_type(8)));
typedef _Float16 f16x2 __attribute__((ext_vector_type(2)));
typedef float    f32x4 __attribute__((ext_vector_type(4)));

typedef __attribute__((address_space(3))) void lds_void_t;
typedef __attribute__((address_space(1))) void glb_void_t;

__device__ __forceinline__ void gload_lds16(const void* g, void* l) {
  __builtin_amdgcn_global_load_lds((const glb_void_t*)g, (lds_void_t*)l, 16, 0, 0);
}

__device__ __forceinline__ float sigmoidf_(float x) {
  float e = __builtin_amdgcn_exp2f(-x * 1.44269504f);
  return __builtin_amdgcn_rcpf(1.0f + e);
}
__device__ __forceinline__ float tanhf_(float x) {
  float e = __builtin_amdgcn_exp2f(x * 2.88539008f);
  return 1.0f - 2.0f * __builtin_amdgcn_rcpf(e + 1.0f);
}
__device__ __forceinline__ float dot2(unsigned w, unsigned h, float acc) {
  return __builtin_amdgcn_fdot2(__builtin_bit_cast(f16x2, w),
                                __builtin_bit_cast(f16x2, h), acc, false);
}
__device__ __forceinline__ unsigned pack2(float a, float b) {
  __half2 h = __floats2half2_rn(a, b);
  return __builtin_bit_cast(unsigned, h);
}
__device__ __forceinline__ float hsel(unsigned w, int hi) {
  __half2 h2 = __builtin_bit_cast(__half2, w);
  return hi ? __high2float(h2) : __low2float(h2);
}

// ---------------- hypernetwork ----------------
__global__ void hyper1(const float* __restrict__ es, const float* __restrict__ W1,
                       const float* __restrict__ b1, float* __restrict__ hE) {
  int b = blockIdx.x, o = threadIdx.x;   // 32 x 256
  float a = b1[o];
  #pragma unroll
  for (int c = 0; c < 16; ++c) a += es[b*16 + c] * W1[o*16 + c];
  hE[b*256 + o] = fmaxf(a, 0.f);
}

__global__ void hyper2(const float* __restrict__ hE,
                       const float* __restrict__ Wbh, const float* __restrict__ bbh,
                       const float* __restrict__ harmb,
                       const float* __restrict__ Wbn, const float* __restrict__ bbn,
                       const float* __restrict__ noiseb, float* __restrict__ effb) {
  int b = blockIdx.x, o = threadIdx.x;
  if (o < NH_) {
    float a = bbh[o] + harmb[o];
    for (int c = 0; c < 256; ++c) a += hE[b*256 + c] * Wbh[o*256 + c];
    effb[b*256 + o] = a;
  } else if (o < NH_ + NM_) {
    int q = o - NH_;
    float a = bbn[q] + noiseb[q];
    for (int c = 0; c < 256; ++c) a += hE[b*256 + c] * Wbn[q*256 + c];
    effb[b*256 + o] = a;
  }
}

// effW[b][o_base+o][h] = baseW[o*512+h] + bd[row] + sum_c Wd[row][c]*hE[b][c]
__global__ __launch_bounds__(256) void hyper3(
    const float* __restrict__ hE, const float* __restrict__ Wd,
    const float* __restrict__ bd, const float* __restrict__ baseW,
    __half* __restrict__ effW, int o_base) {
  __shared__ float wl[256*33];
  __shared__ float hEl[32*256];
  int tid = threadIdx.x;
  int row0 = blockIdx.x * 256;
  #pragma unroll
  for (int i = 0; i < 32; ++i) hEl[i*256 + tid] = hE[i*256 + tid];
  float acc[32];
  #pragma unroll
  for (int b = 0; b < 32; ++b) acc[b] = 0.f;
  for (int cc = 0; cc < 256; cc += 32) {
    __syncthreads();
    #pragma unroll
    for (int i = 0; i < 32; ++i) {
      int idx = i*256 + tid;
      int r = idx >> 5, c = idx & 31;
      wl[r*33 + c] = Wd[(size_t)(row0 + r)*256 + cc + c];
    }
    __syncthreads();
    #pragma unroll
    for (int c = 0; c < 32; ++c) {
      float w = wl[tid*33 + c];
      #pragma unroll
      for (int b = 0; b < 32; ++b) acc[b] += w * hEl[b*256 + cc + c];
    }
  }
  int row = row0 + tid;
  int o = row >> 9, h = row & 511;
  float base = baseW[row] + bd[row];
  #pragma unroll
  for (int b = 0; b < 32; ++b) {
    effW[((size_t)b*256 + o_base + o)*512 + h] = (__half)(acc[b] + base);
  }
}

// ---------------- converts ----------------
__global__ void cvt_f16(const float* __restrict__ in, __half* __restrict__ out, int n) {
  int i = blockIdx.x*256 + threadIdx.x;
  if (i < n) out[i] = (__half)in[i];
}

// Wp3[(w*32 + k)*384 + t]: WG w (unit-block), thread t (rr=t>>1 row, ch=t&1 col-half),
// k-th 8-col quad. row = g*512 + w*64 + j (g=rr>>6, j=rr&63), cols = ch*256 + k*8 ..+8
__global__ void pack_whh3(const float* __restrict__ Whh, uint4* __restrict__ Wp3) {
  int idx = blockIdx.x*256 + threadIdx.x;    // 8*32*384 = 98304
  int t = idx % 384;
  int k = (idx / 384) & 31;
  int w = idx / (384*32);
  int rr = t >> 1, ch = t & 1;
  int g = rr >> 6, j = rr & 63;
  int row = g*512 + w*64 + j;
  int col0 = ch*256 + k*8;
  const float* src = Whh + (size_t)row*512 + col0;
  uint4 o;
  o.x = pack2(src[0], src[1]);
  o.y = pack2(src[2], src[3]);
  o.z = pack2(src[4], src[5]);
  o.w = pack2(src[6], src[7]);
  Wp3[idx] = o;
}

// ---------------- pre layer (per chunk) ----------------
__global__ void pre_kernel(const float* __restrict__ f0, const float* __restrict__ loud,
                           const float* __restrict__ preW, const float* __restrict__ preb,
                           __half* __restrict__ xpre, int CH, int c0) {
  int b = blockIdx.y;
  int idx = blockIdx.x*256 + threadIdx.x;    // CH*512
  int t = idx >> 9, h = idx & 511;
  int mg = b*T_ + c0 + t;
  float v = f0[mg]*preW[h*2+0] + loud[mg]*preW[h*2+1] + preb[h];
  v = v >= 0.f ? v : 0.01f*v;
  xpre[((size_t)b*CH + t)*512 + h] = (__half)v;
}

// ---------------- trunk GEMM (NT, K=512, 128x128 tile, f16 MFMA) ----------------
template<int ACT>
__global__ __launch_bounds__(256) void gemm_nt(
    const __half* __restrict__ A, const __half* __restrict__ B,
    __half* __restrict__ C, const float* __restrict__ bias, int N) {
  constexpr int K = 512;
  __shared__ __align__(16) __half As[128*64];
  __shared__ __align__(16) __half Bs[128*64];
  int tid = threadIdx.x;
  int bx = blockIdx.x, by = blockIdx.y;
  const __half* Ab = A + (size_t)bx*128*K;
  const __half* Bb = B + (size_t)by*128*K;
  f32x4 acc[4][4] = {};
  int lane = tid & 63;
  int wv = tid >> 6, wr = wv >> 1, wc = wv & 1;
  int lr = lane & 15, lk = lane >> 4;

  for (int kt = 0; kt < K/64; ++kt) {
    #pragma unroll
    for (int j = 0; j < 4; ++j) {
      int idx = j*256 + tid;
      int row = idx >> 3, seg = idx & 7;
      const __half* gpA = Ab + (size_t)row*K + kt*64 + seg*8;
      const __half* gpB = Bb + (size_t)row*K + kt*64 + seg*8;
      __half* lpA = As + (size_t)(j*256 + (tid & ~63))*8;
      __half* lpB = Bs + (size_t)(j*256 + (tid & ~63))*8;
      gload_lds16(gpA, lpA);
      gload_lds16(gpB, lpB);
    }
    __syncthreads();
    #pragma unroll
    for (int ks = 0; ks < 2; ++ks) {
      f16x8 af[4], bf[4];
      #pragma unroll
      for (int i = 0; i < 4; ++i)
        af[i] = *(const f16x8*)(As + (wr*64 + i*16 + lr)*64 + ks*32 + lk*8);
      #pragma unroll
      for (int j2 = 0; j2 < 4; ++j2)
        bf[j2] = *(const f16x8*)(Bs + (wc*64 + j2*16 + lr)*64 + ks*32 + lk*8);
      #pragma unroll
      for (int i = 0; i < 4; ++i)
        #pragma unroll
        for (int j2 = 0; j2 < 4; ++j2)
          acc[i][j2] = __builtin_amdgcn_mfma_f32_16x16x32_f16(af[i], bf[j2], acc[i][j2], 0, 0, 0);
    }
    __syncthreads();
  }

  #pragma unroll
  for (int j2 = 0; j2 < 4; ++j2) {
    int col = by*128 + wc*64 + j2*16 + lr;
    float bv = bias[col];
    #pragma unroll
    for (int i = 0; i < 4; ++i) {
      int row0 = bx*128 + wr*64 + i*16 + lk*4;
      #pragma unroll
      for (int r = 0; r < 4; ++r) {
        float v = acc[i][j2][r] + bv;
        if (ACT == 1) v = v >= 0.f ? v : 0.01f*v;
        C[(size_t)(row0 + r)*N + col] = (__half)v;
      }
    }
  }
}

// ---------------- heads GEMM: per-batch modulated weights, sigmoid, fp32 out ----------------
__global__ __launch_bounds__(256) void heads_gemm(
    const __half* __restrict__ Apc, const __half* __restrict__ effW,
    const float* __restrict__ effb, float* __restrict__ out, int CH, int c0) {
  constexpr int K = 512;
  __shared__ __align__(16) __half As[128*64];
  __shared__ __align__(16) __half Bs[128*64];
  int tid = threadIdx.x;
  int bx = blockIdx.x, by = blockIdx.y, b = blockIdx.z;
  const __half* Ab = Apc + (size_t)b*CH*K;
  const __half* Bb = effW + ((size_t)b*256 + (size_t)by*128)*K;
  f32x4 acc[4][4] = {};
  int lane = tid & 63;
  int wv = tid >> 6, wr = wv >> 1, wc = wv & 1;
  int lr = lane & 15, lk = lane >> 4;

  for (int kt = 0; kt < K/64; ++kt) {
    #pragma unroll
    for (int j = 0; j < 4; ++j) {
      int idx = j*256 + tid;
      int row = idx >> 3, seg = idx & 7;
      int ar = bx*128 + row; if (ar > CH-1) ar = CH-1;
      const __half* gpA = Ab + (size_t)ar*K + kt*64 + seg*8;
      const __half* gpB = Bb + (size_t)row*K + kt*64 + seg*8;
      __half* lpA = As + (size_t)(j*256 + (tid & ~63))*8;
      __half* lpB = Bs + (size_t)(j*256 + (tid & ~63))*8;
      gload_lds16(gpA, lpA);
      gload_lds16(gpB, lpB);
    }
    __syncthreads();
    #pragma unroll
    for (int ks = 0; ks < 2; ++ks) {
      f16x8 af[4], bf[4];
      #pragma unroll
      for (int i = 0; i < 4; ++i)
        af[i] = *(const f16x8*)(As + (wr*64 + i*16 + lr)*64 + ks*32 + lk*8);
      #pragma unroll
      for (int j2 = 0; j2 < 4; ++j2)
        bf[j2] = *(const f16x8*)(Bs + (wc*64 + j2*16 + lr)*64 + ks*32 + lk*8);
      #pragma unroll
      for (int i = 0; i < 4; ++i)
        #pragma unroll
        for (int j2 = 0; j2 < 4; ++j2)
          acc[i][j2] = __builtin_amdgcn_mfma_f32_16x16x32_f16(af[i], bf[j2], acc[i][j2], 0, 0, 0);
    }
    __syncthreads();
  }

  #pragma unroll
  for (int j2 = 0; j2 < 4; ++j2) {
    int o = by*128 + wc*64 + j2*16 + lr;
    if (o < NH_ + NM_) {
      float bv = effb[b*256 + o];
      #pragma unroll
      for (int i = 0; i < 4; ++i) {
        #pragma unroll
        for (int r = 0; r < 4; ++r) {
          int trow = bx*128 + wr*64 + i*16 + lk*4 + r;
          if (trow < CH) {
            int tg = c0 + trow;
            float v = sigmoidf_(acc[i][j2][r] + bv);
            if (o < NH_)
              out[((size_t)b*T_ + tg)*NH_ + o] = v;
            else
              out[(size_t)B_*T_*NH_ + ((size_t)b*T_ + tg)*NM_ + (o - NH_)] = v;
          }
        }
      }
    }
  }
}

// ---------------- GRU scan: 8 WGs/batch, single-RT u64 tagged exchange ----------
// W_hh split across 8 CUs/batch (64 units x 3 gates = 192 KB = 128 VGPR on 384 thr,
// inline-asm loads: non-rematerializable). Exchange: (tag<<32 | h-pair) in ONE
// relaxed agent u64 atomic store; 224 remote pollers spin on their own slot (tag
// match => data present) -> 1 LLC round trip instead of 3 (round-6: store-ack +
// flag + gather = 2.7us/step). Own 32 slots come from LDS (sval). Tag safety:
// per-slot tags strictly increase within a launch; first fresh write (tag 1/2)
// kills stale (tags >= CH-1 >= 19) and 0xAA poison -> no reset, graph-safe.
// hq padded (ch*132): ch0 banks 0-3, ch1 banks 4-7 -> conflict-free ds_read_b128
// (round-6: 1.97e8 conflict cycles from the 512B-apart two-address pattern).
#define LOADW(k) { const uint4* p = Wp3 + ((size_t)(w*32 + (k)))*384 + t; \
  asm volatile("global_load_dwordx4 %0, %1, off" : "=v"(wq_##k) : "v"(p) : "memory"); }

#define DOTW(k, A) { uint4 hv = *(const uint4*)&hq[ch*132 + (k)*4]; \
  A = dot2(wq_##k.x, hv.x, A); A = dot2(wq_##k.y, hv.y, A); \
  A = dot2(wq_##k.z, hv.z, A); A = dot2(wq_##k.w, hv.w, A); }

__global__ __launch_bounds__(512) __attribute__((amdgpu_waves_per_eu(2, 4)))
void gru_scan8(
    const uint4* __restrict__ Wp3, const __half* __restrict__ gi_c,
    const float* __restrict__ bhh, __half* __restrict__ ys_c,
    float* __restrict__ hstate, unsigned long long* __restrict__ xch64,
    int CH, int first) {
  int wg = blockIdx.x;
  int b = wg & 31;            // batch
  int w = wg >> 5;            // unit-block 0..7 (units w*64 .. +64)
  int t = threadIdx.x;
  int rr = t >> 1, ch = t & 1;
  bool wact = (t < 384);      // waves 0-5 hold weights

  __shared__ __align__(16) unsigned hq[264];   // h packed f16x2; [0..127]=ch0, [132..259]=ch1
  __shared__ float part[384];                  // [row 0..191][colhalf]
  __shared__ float gil[192];                   // gi slices for combine
  __shared__ unsigned sval[32];                // own h-slice (LDS bypass)

  uint4 wq_0{},wq_1{},wq_2{},wq_3{},wq_4{},wq_5{},wq_6{},wq_7{},
        wq_8{},wq_9{},wq_10{},wq_11{},wq_12{},wq_13{},wq_14{},wq_15{},
        wq_16{},wq_17{},wq_18{},wq_19{},wq_20{},wq_21{},wq_22{},wq_23{},
        wq_24{},wq_25{},wq_26{},wq_27{},wq_28{},wq_29{},wq_30{},wq_31{};
  if (wact) {
    LOADW(0)  LOADW(1)  LOADW(2)  LOADW(3)  LOADW(4)  LOADW(5)  LOADW(6)  LOADW(7)
    LOADW(8)  LOADW(9)  LOADW(10) LOADW(11) LOADW(12) LOADW(13) LOADW(14) LOADW(15)
    LOADW(16) LOADW(17) LOADW(18) LOADW(19) LOADW(20) LOADW(21) LOADW(22) LOADW(23)
    LOADW(24) LOADW(25) LOADW(26) LOADW(27) LOADW(28) LOADW(29) LOADW(30) LOADW(31)
  }
  asm volatile("s_waitcnt vmcnt(0)" ::: "memory");
  __builtin_amdgcn_sched_barrier(0);

  // combine-thread biases (t<32 handles units 2t, 2t+1)
  float br0=0.f,br1=0.f,bz0=0.f,bz1=0.f,bn0=0.f,bn1=0.f;
  if (t < 32) {
    int u0 = w*64 + 2*t;
    br0 = bhh[u0];        br1 = bhh[u0+1];
    bz0 = bhh[512+u0];    bz1 = bhh[512+u0+1];
    bn0 = bhh[1024+u0];   bn1 = bhh[1024+u0+1];
  }

  if (t < 256) {
    unsigned hv0 = first ? 0u : pack2(hstate[b*512 + 2*t], hstate[b*512 + 2*t + 1]);
    hq[t < 128 ? t : t + 4] = hv0;
  }
  __syncthreads();

  const __half* gib = gi_c + (size_t)b*CH*1536;
  __half* ysb = ys_c + (size_t)b*CH*512;

  for (int s = 0; s < CH; ++s) {
    int p = s & 1;
    unsigned long long* xp64 = xch64 + ((size_t)p*32 + b)*256;
    // gi for the combine (3 gates x own 64 units), issued early, consumed post-gemv
    float giv = 0.f;
    if (t < 192) giv = (float)gib[(size_t)s*1536 + (t >> 6)*512 + w*64 + (t & 63)];

    if (wact) {
      float a0 = 0.f, a1 = 0.f, a2 = 0.f, a3 = 0.f;
      DOTW(0,a0)  DOTW(1,a1)  DOTW(2,a2)  DOTW(3,a3)
      DOTW(4,a0)  DOTW(5,a1)  DOTW(6,a2)  DOTW(7,a3)
      DOTW(8,a0)  DOTW(9,a1)  DOTW(10,a2) DOTW(11,a3)
      DOTW(12,a0) DOTW(13,a1) DOTW(14,a2) DOTW(15,a3)
      DOTW(16,a0) DOTW(17,a1) DOTW(18,a2) DOTW(19,a3)
      DOTW(20,a0) DOTW(21,a1) DOTW(22,a2) DOTW(23,a3)
      DOTW(24,a0) DOTW(25,a1) DOTW(26,a2) DOTW(27,a3)
      DOTW(28,a0) DOTW(29,a1) DOTW(30,a2) DOTW(31,a3)
      part[rr*2 + ch] = (a0 + a1) + (a2 + a3);
      if (t < 192) gil[t] = giv;
    }
    __syncthreads();

    if (t < 32) {
      int j0 = 2*t, j1 = 2*t + 1;
      float ghr0 = part[j0*2] + part[j0*2+1] + br0;
      float ghr1 = part[j1*2] + part[j1*2+1] + br1;
      float ghz0 = part[(64+j0)*2] + part[(64+j0)*2+1] + bz0;
      float ghz1 = part[(64+j1)*2] + part[(64+j1)*2+1] + bz1;
      float ghn0 = part[(128+j0)*2] + part[(128+j0)*2+1] + bn0;
      float ghn1 = part[(128+j1)*2] + part[(128+j1)*2+1] + bn1;
      float r0 = sigmoidf_(gil[j0] + ghr0);
      float r1 = sigmoidf_(gil[j1] + ghr1);
      float z0 = sigmoidf_(gil[64+j0] + ghz0);
      float z1 = sigmoidf_(gil[64+j1] + ghz1);
      float n0 = tanhf_(gil[128+j0] + r0*ghn0);
      float n1 = tanhf_(gil[128+j1] + r1*ghn1);
      int gidx = w*32 + t;
      unsigned hold = hq[gidx < 128 ? gidx : gidx + 4];
      float h0 = (1.f - z0)*n0 + z0*hsel(hold, 0);
      float h1 = (1.f - z1)*n1 + z1*hsel(hold, 1);
      unsigned hv = pack2(h0, h1);
      *(unsigned*)&ysb[(size_t)s*512 + w*64 + j0] = hv;            // ys (f16 pair)
      unsigned long long tv = ((unsigned long long)(unsigned)(s + 1) << 32)
                              | (unsigned long long)hv;
      __hip_atomic_store(&xp64[w*32 + t], tv,
                         __ATOMIC_RELAXED, __HIP_MEMORY_SCOPE_AGENT);
      sval[t] = hv;
      if (s == CH - 1) {
        hstate[b*512 + w*64 + j0] = h0;
        hstate[b*512 + w*64 + j1] = h1;
      }
    }
    __syncthreads();
    if (t < 256) {
      unsigned hv;
      if ((t >> 5) == w) {
        hv = sval[t & 31];
      } else {
        unsigned long long v;
        do {
          v = __hip_atomic_load(&xp64[t], __ATOMIC_RELAXED, __HIP_MEMORY_SCOPE_AGENT);
        } while ((unsigned)(v >> 32) != (unsigned)(s + 1));
        hv = (unsigned)v;
      }
      hq[t < 128 ? t : t + 4] = hv;
    }
    __syncthreads();
  }
}

// ---------------- launch ----------------
extern "C" void kernel_launch(void* const* d_in, const int* in_sizes, int n_in,
                              void* d_out, int out_size, void* d_ws, size_t ws_size,
                              hipStream_t stream) {
  const float* f0     = (const float*)d_in[0];
  const float* loud   = (const float*)d_in[1];
  const float* es     = (const float*)d_in[2];
  const float* preW   = (const float*)d_in[3];
  const float* preb   = (const float*)d_in[4];
  const float* Wih    = (const float*)d_in[5];
  const float* Whh    = (const float*)d_in[6];
  const float* b_ih   = (const float*)d_in[7];
  const float* b_hh   = (const float*)d_in[8];
  const float* postW  = (const float*)d_in[9];
  const float* postb  = (const float*)d_in[10];
  const float* harmW  = (const float*)d_in[11];
  const float* harmb  = (const float*)d_in[12];
  const float* noiseW = (const float*)d_in[13];
  const float* noiseb = (const float*)d_in[14];
  const float* hypW1  = (const float*)d_in[15];
  const float* hypb1  = (const float*)d_in[16];
  const float* Wdh    = (const float*)d_in[17];
  const float* bdh    = (const float*)d_in[18];
  const float* Wbh    = (const float*)d_in[19];
  const float* bbh    = (const float*)d_in[20];
  const float* Wdn    = (const float*)d_in[21];
  const float* bdn    = (const float*)d_in[22];
  const float* Wbn    = (const float*)d_in[23];
  const float* bbn    = (const float*)d_in[24];
  (void)in_sizes; (void)n_in; (void)out_size;

  const size_t FIXED = 13312ull*1024ull;   // ~13 MB fixed region
  int CH = 20;
  {
    const int opts[8] = {2000, 1000, 500, 400, 200, 100, 40, 20};
    for (int i = 0; i < 8; ++i) {
      size_t need = FIXED + (size_t)opts[i] * 163840ull + 65536ull;
      if (need <= ws_size) { CH = opts[i]; break; }
    }
  }
  const int NC = T_ / CH;
  const int Mc = B_ * CH;

  char* w = (char*)d_ws;
  size_t off = 0;
  auto alloc = [&](size_t bytes) -> void* {
    void* p = (void*)(w + off);
    off += (bytes + 255) & ~(size_t)255;
    return p;
  };
  float*    hE      = (float*)alloc((size_t)32*256*4);
  float*    effb    = (float*)alloc((size_t)32*256*4);
  float*    hstate  = (float*)alloc((size_t)32*512*4);
  __half*   effW    = (__half*)alloc((size_t)32*256*512*2);
  __half*   Wih16   = (__half*)alloc((size_t)1536*512*2);
  __half*   postW16 = (__half*)alloc((size_t)512*512*2);
  uint4*    Wp3     = (uint4*)alloc((size_t)8*32*384*16 + 4096);
  unsigned long long* xch64 = (unsigned long long*)alloc((size_t)2*32*256*8);
  __half*   xpre    = (__half*)alloc((size_t)Mc*512*2);
  __half*   gibuf   = (__half*)alloc((size_t)Mc*1536*2);
  __half*   ysbuf   = (__half*)alloc((size_t)Mc*512*2);
  __half*   postc   = xpre;   // xpre dead after gi GEMM

  hyper1<<<32, 256, 0, stream>>>(es, hypW1, hypb1, hE);
  hyper2<<<32, 256, 0, stream>>>(hE, Wbh, bbh, harmb, Wbn, bbn, noiseb, effb);
  hyper3<<<200, 256, 0, stream>>>(hE, Wdh, bdh, harmW, effW, 0);
  hyper3<<<130, 256, 0, stream>>>(hE, Wdn, bdn, noiseW, effW, NH_);
  cvt_f16<<<(1536*512)/256, 256, 0, stream>>>(Wih, Wih16, 1536*512);
  cvt_f16<<<(512*512)/256, 256, 0, stream>>>(postW, postW16, 512*512);
  pack_whh3<<<384, 256, 0, stream>>>(Whh, Wp3);

  for (int c = 0; c < NC; ++c) {
    int c0 = c * CH;
    pre_kernel<<<dim3(CH*2, 32), 256, 0, stream>>>(f0, loud, preW, preb, xpre, CH, c0);
    gemm_nt<0><<<dim3(Mc/128, 12), 256, 0, stream>>>(xpre, Wih16, gibuf, b_ih, 1536);
    gru_scan8<<<256, 512, 0, stream>>>(Wp3, gibuf, b_hh, ysbuf, hstate, xch64,
                                       CH, c == 0 ? 1 : 0);
    gemm_nt<1><<<dim3(Mc/128, 4), 256, 0, stream>>>(ysbuf, postW16, postc, postb, 512);
    heads_gemm<<<dim3((CH+127)/128, 2, 32), 256, 0, stream>>>(postc, effW, effb,
                                                              (float*)d_out, CH, c0);
  }
}